// Round 2
// baseline (640.403 us; speedup 1.0000x reference)
//
#include <hip/hip_runtime.h>
#include <cmath>
#include <climits>

static constexpr int T_DIM = 2000;
static constexpr int N_DIM = 64;
static constexpr int V_DIM = 1000;   // 250 float4 per row
static constexpr int BLANK = 0;

// ---------------------------------------------------------------------------
// Kernel 1: one wave (64 lanes) per (t,n) row. Row is V=1000 contiguous fp32.
// argmax(logits) and maxlogp = -log(sum exp(x - max)).
// Writes transposed (N,T) so kernel 2 reads coalesced.
// Structure: fmax tree (short dep chain) -> wave max (6 shuffles) ->
// exp-sum and index-recovery run as independent streams -> 6+6 shuffles.
// ---------------------------------------------------------------------------
__global__ __launch_bounds__(256) void ctc_rowreduce(
    const float* __restrict__ logits,
    float* __restrict__ maxlpT,   // (N, T)
    int*   __restrict__ argmaxT)  // (N, T)
{
    const int lane = threadIdx.x & 63;
    const int wv   = threadIdx.x >> 6;
    const int row  = blockIdx.x * 4 + wv;        // row = t*N + n, always < T*N

    const float4* p = reinterpret_cast<const float4*>(logits + (size_t)row * V_DIM);

    // 250 float4 per row; lanes 0..57 take a 4th chunk. -INF fill makes the
    // tail vanish from both max and exp-sum with zero divergence in compute.
    float4 r0 = p[lane];
    float4 r1 = p[lane + 64];
    float4 r2 = p[lane + 128];
    float4 r3 = (lane < 58) ? p[lane + 192]
                            : make_float4(-INFINITY, -INFINITY, -INFINITY, -INFINITY);

    // local max: pure fmax tree (v_max3-friendly, depth ~3)
    float m0 = fmaxf(fmaxf(r0.x, r0.y), fmaxf(r0.z, r0.w));
    float m1 = fmaxf(fmaxf(r1.x, r1.y), fmaxf(r1.z, r1.w));
    float m2 = fmaxf(fmaxf(r2.x, r2.y), fmaxf(r2.z, r2.w));
    float m3 = fmaxf(fmaxf(r3.x, r3.y), fmaxf(r3.z, r3.w));
    float m  = fmaxf(fmaxf(m0, m1), fmaxf(m2, m3));

    // wave max: 6 single shuffles
    #pragma unroll
    for (int off = 32; off >= 1; off >>= 1)
        m = fmaxf(m, __shfl_xor(m, off, 64));

    // exp-sum (stream A) ...
    float s0 = __expf(r0.x - m) + __expf(r0.y - m) + __expf(r0.z - m) + __expf(r0.w - m);
    float s1 = __expf(r1.x - m) + __expf(r1.y - m) + __expf(r1.z - m) + __expf(r1.w - m);
    float s2 = __expf(r2.x - m) + __expf(r2.y - m) + __expf(r2.z - m) + __expf(r2.w - m);
    float s3 = __expf(r3.x - m) + __expf(r3.y - m) + __expf(r3.z - m) + __expf(r3.w - m);
    float s  = (s0 + s1) + (s2 + s3);

    // ... index recovery (stream B, independent compares -> min index where == m)
    // min-index-where-equal == jnp.argmax first-occurrence tie-break.
    const int b = 4 * lane;
    int idx = INT_MAX;
#define SEL(v, i) idx = min(idx, (v) == m ? (i) : INT_MAX)
    SEL(r0.x, b + 0);   SEL(r0.y, b + 1);   SEL(r0.z, b + 2);   SEL(r0.w, b + 3);
    SEL(r1.x, b + 256); SEL(r1.y, b + 257); SEL(r1.z, b + 258); SEL(r1.w, b + 259);
    SEL(r2.x, b + 512); SEL(r2.y, b + 513); SEL(r2.z, b + 514); SEL(r2.w, b + 515);
    SEL(r3.x, b + 768); SEL(r3.y, b + 769); SEL(r3.z, b + 770); SEL(r3.w, b + 771);
#undef SEL

    #pragma unroll
    for (int off = 32; off >= 1; off >>= 1) {
        s   += __shfl_xor(s, off, 64);
        idx  = min(idx, __shfl_xor(idx, off, 64));
    }

    if (lane == 0) {
        const int t = row >> 6;            // row / N_DIM (N=64)
        const int n = row & (N_DIM - 1);
        maxlpT[n * T_DIM + t] = -__logf(s);   // m - (m + log s)
        argmaxT[n * T_DIM + t] = idx;
    }
}

// ---------------------------------------------------------------------------
// Kernel 2: one block (256 threads = 4 waves) per batch element n.
// keep mask -> wave shuffle scan (2 barriers total) -> LDS compaction -> out.
// Output layout (all float): [ score(N) | paths(T*N, (T,N) order) | out_lens(N) ]
// ---------------------------------------------------------------------------
__global__ __launch_bounds__(256) void ctc_scan(
    const float* __restrict__ maxlpT,
    const int*   __restrict__ argmaxT,
    const int*   __restrict__ in_lens,
    float*       __restrict__ out)
{
    constexpr int CHUNK = 8;               // 256*8 = 2048 >= T; 2000 % 8 == 0
    const int n    = blockIdx.x;
    const int tid  = threadIdx.x;
    const int lane = tid & 63;
    const int w    = tid >> 6;
    const int in_len = in_lens[n];
    const int*   am = argmaxT + n * T_DIM;
    const float* ml = maxlpT + n * T_DIM;

    __shared__ int   buf[T_DIM];           // compacted path values (8000 B)
    __shared__ int   wtot[4];
    __shared__ float wsum[4];

    const int t0 = tid * CHUNK;
    const bool live = (t0 < T_DIM);        // tid < 250

    int   my_am[CHUNK];
    bool  my_keep[CHUNK];
    int   cnt = 0;
    float sc  = 0.f;

    if (live) {
        const int4*   ap = reinterpret_cast<const int4*>(am + t0);     // 32B-aligned
        const float4* fp = reinterpret_cast<const float4*>(ml + t0);
        int4   a0 = ap[0], a1 = ap[1];
        float4 f0 = fp[0], f1 = fp[1];
        my_am[0] = a0.x; my_am[1] = a0.y; my_am[2] = a0.z; my_am[3] = a0.w;
        my_am[4] = a1.x; my_am[5] = a1.y; my_am[6] = a1.z; my_am[7] = a1.w;
        const float fv[CHUNK] = {f0.x, f0.y, f0.z, f0.w, f1.x, f1.y, f1.z, f1.w};

        int prev = (t0 > 0) ? am[t0 - 1] : -1;  // -1 never matches 0..V-1
        #pragma unroll
        for (int k = 0; k < CHUNK; ++k) {
            const int t = t0 + k;
            const int a = my_am[k];
            const bool kp = (a != BLANK) && (a != prev) && (t < in_len);
            my_keep[k] = kp;
            cnt += kp ? 1 : 0;
            if (t < in_len) sc += fv[k];
            prev = a;
        }
    } else {
        #pragma unroll
        for (int k = 0; k < CHUNK; ++k) { my_am[k] = 0; my_keep[k] = false; }
    }

    // wave-level inclusive scan of cnt (no barriers)
    int inc = cnt;
    #pragma unroll
    for (int off = 1; off < 64; off <<= 1) {
        int v = __shfl_up(inc, off, 64);
        if (lane >= off) inc += v;
    }

    // wave-level score sum
    float ss = sc;
    #pragma unroll
    for (int off = 32; off >= 1; off >>= 1)
        ss += __shfl_xor(ss, off, 64);

    if (lane == 63) wtot[w] = inc;
    if (lane == 0)  wsum[w] = ss;
    __syncthreads();                       // barrier 1

    int woff = 0;
    #pragma unroll
    for (int i = 0; i < 4; ++i) woff += (i < w) ? wtot[i] : 0;
    const int out_len = wtot[0] + wtot[1] + wtot[2] + wtot[3];

    // scatter kept values into LDS compaction buffer
    int pos = woff + inc - cnt;            // exclusive global prefix
    #pragma unroll
    for (int k = 0; k < CHUNK; ++k) {
        if (my_keep[k]) buf[pos++] = my_am[k];
    }
    __syncthreads();                       // barrier 2

    // paths: compacted inside out_len, raw argmax outside; (T,N) layout
    if (live) {
        #pragma unroll
        for (int k = 0; k < CHUNK; ++k) {
            const int t = t0 + k;
            const int v = (t < out_len) ? buf[t] : my_am[k];
            out[N_DIM + (size_t)t * N_DIM + n] = (float)v;
        }
    }

    if (tid == 0) {
        out[n] = (wsum[0] + wsum[1]) + (wsum[2] + wsum[3]);
        out[N_DIM + (size_t)T_DIM * N_DIM + n] = (float)out_len;
    }
}

extern "C" void kernel_launch(void* const* d_in, const int* in_sizes, int n_in,
                              void* d_out, int out_size, void* d_ws, size_t ws_size,
                              hipStream_t stream)
{
    const float* logits  = (const float*)d_in[0];
    const int*   in_lens = (const int*)d_in[1];
    float* out = (float*)d_out;

    float* maxlpT  = (float*)d_ws;
    int*   argmaxT = (int*)((char*)d_ws + (size_t)T_DIM * N_DIM * sizeof(float));

    ctc_rowreduce<<<(T_DIM * N_DIM) / 4, 256, 0, stream>>>(logits, maxlpT, argmaxT);
    ctc_scan<<<N_DIM, 256, 0, stream>>>(maxlpT, argmaxT, in_lens, out);
}

// Round 4
// 609.282 us; speedup vs baseline: 1.0511x; 1.0511x over previous
//
#include <hip/hip_runtime.h>
#include <cmath>
#include <climits>

static constexpr int T_DIM = 2000;
static constexpr int N_DIM = 64;
static constexpr int V_DIM = 1000;   // 250 float4 per row
static constexpr int BLANK = 0;

// native clang vector type: __builtin_nontemporal_load accepts these
// (HIP_vector_type float4 is a struct and is rejected)
typedef float vfloat4 __attribute__((ext_vector_type(4)));

// ---------------------------------------------------------------------------
// Kernel 1: one wave (64 lanes) per TWO (t,n) rows. Row = V=1000 contiguous
// fp32. 8 dwordx4 loads/lane back-to-back (2x MLP vs 1-row version); the two
// rows' reduction chains are independent -> shuffle/exp latency interleaves.
// argmax(logits) and maxlogp = -log(sum exp(x - max)).
// Writes transposed (N,T) so kernel 2 reads coalesced.
// ---------------------------------------------------------------------------
__global__ __launch_bounds__(256) void ctc_rowreduce(
    const float* __restrict__ logits,
    float* __restrict__ maxlpT,   // (N, T)
    int*   __restrict__ argmaxT)  // (N, T)
{
    const int lane = threadIdx.x & 63;
    const int wv   = threadIdx.x >> 6;
    const int rowA = (blockIdx.x * 4 + wv) * 2;  // rows rowA, rowA+1 (< T*N)

    const vfloat4* pA = reinterpret_cast<const vfloat4*>(logits + (size_t)rowA * V_DIM);
    const vfloat4* pB = reinterpret_cast<const vfloat4*>(logits + (size_t)(rowA + 1) * V_DIM);

    const bool has3 = (lane < 58);
    const vfloat4 ninf = {-INFINITY, -INFINITY, -INFINITY, -INFINITY};

    // 8 streaming loads issued back-to-back (nontemporal: zero reuse, spare L2)
    vfloat4 a0 = __builtin_nontemporal_load(pA + lane);
    vfloat4 a1 = __builtin_nontemporal_load(pA + lane + 64);
    vfloat4 a2 = __builtin_nontemporal_load(pA + lane + 128);
    vfloat4 b0 = __builtin_nontemporal_load(pB + lane);
    vfloat4 b1 = __builtin_nontemporal_load(pB + lane + 64);
    vfloat4 b2 = __builtin_nontemporal_load(pB + lane + 128);
    vfloat4 a3 = has3 ? __builtin_nontemporal_load(pA + lane + 192) : ninf;
    vfloat4 b3 = has3 ? __builtin_nontemporal_load(pB + lane + 192) : ninf;

    // local max trees (independent, v_max3-friendly)
    float mA = fmaxf(fmaxf(fmaxf(a0.x, a0.y), fmaxf(a0.z, a0.w)),
              fmaxf(fmaxf(fmaxf(a1.x, a1.y), fmaxf(a1.z, a1.w)),
              fmaxf(fmaxf(fmaxf(a2.x, a2.y), fmaxf(a2.z, a2.w)),
                    fmaxf(fmaxf(a3.x, a3.y), fmaxf(a3.z, a3.w)))));
    float mB = fmaxf(fmaxf(fmaxf(b0.x, b0.y), fmaxf(b0.z, b0.w)),
              fmaxf(fmaxf(fmaxf(b1.x, b1.y), fmaxf(b1.z, b1.w)),
              fmaxf(fmaxf(fmaxf(b2.x, b2.y), fmaxf(b2.z, b2.w)),
                    fmaxf(fmaxf(b3.x, b3.y), fmaxf(b3.z, b3.w)))));

    // wave max: two interleaved 6-step chains
    #pragma unroll
    for (int off = 32; off >= 1; off >>= 1) {
        mA = fmaxf(mA, __shfl_xor(mA, off, 64));
        mB = fmaxf(mB, __shfl_xor(mB, off, 64));
    }

    // exp-sums (two independent streams)
    float sA = (__expf(a0.x - mA) + __expf(a0.y - mA) + __expf(a0.z - mA) + __expf(a0.w - mA))
             + (__expf(a1.x - mA) + __expf(a1.y - mA) + __expf(a1.z - mA) + __expf(a1.w - mA))
             + (__expf(a2.x - mA) + __expf(a2.y - mA) + __expf(a2.z - mA) + __expf(a2.w - mA))
             + (__expf(a3.x - mA) + __expf(a3.y - mA) + __expf(a3.z - mA) + __expf(a3.w - mA));
    float sB = (__expf(b0.x - mB) + __expf(b0.y - mB) + __expf(b0.z - mB) + __expf(b0.w - mB))
             + (__expf(b1.x - mB) + __expf(b1.y - mB) + __expf(b1.z - mB) + __expf(b1.w - mB))
             + (__expf(b2.x - mB) + __expf(b2.y - mB) + __expf(b2.z - mB) + __expf(b2.w - mB))
             + (__expf(b3.x - mB) + __expf(b3.y - mB) + __expf(b3.z - mB) + __expf(b3.w - mB));

    // index recovery: min index where == m (== jnp.argmax first-occurrence)
    const int b = 4 * lane;
    int idxA = INT_MAX, idxB = INT_MAX;
#define SEL(dst, v, m, i) dst = min(dst, (v) == (m) ? (i) : INT_MAX)
    SEL(idxA, a0.x, mA, b + 0);   SEL(idxA, a0.y, mA, b + 1);   SEL(idxA, a0.z, mA, b + 2);   SEL(idxA, a0.w, mA, b + 3);
    SEL(idxA, a1.x, mA, b + 256); SEL(idxA, a1.y, mA, b + 257); SEL(idxA, a1.z, mA, b + 258); SEL(idxA, a1.w, mA, b + 259);
    SEL(idxA, a2.x, mA, b + 512); SEL(idxA, a2.y, mA, b + 513); SEL(idxA, a2.z, mA, b + 514); SEL(idxA, a2.w, mA, b + 515);
    SEL(idxA, a3.x, mA, b + 768); SEL(idxA, a3.y, mA, b + 769); SEL(idxA, a3.z, mA, b + 770); SEL(idxA, a3.w, mA, b + 771);
    SEL(idxB, b0.x, mB, b + 0);   SEL(idxB, b0.y, mB, b + 1);   SEL(idxB, b0.z, mB, b + 2);   SEL(idxB, b0.w, mB, b + 3);
    SEL(idxB, b1.x, mB, b + 256); SEL(idxB, b1.y, mB, b + 257); SEL(idxB, b1.z, mB, b + 258); SEL(idxB, b1.w, mB, b + 259);
    SEL(idxB, b2.x, mB, b + 512); SEL(idxB, b2.y, mB, b + 513); SEL(idxB, b2.z, mB, b + 514); SEL(idxB, b2.w, mB, b + 515);
    SEL(idxB, b3.x, mB, b + 768); SEL(idxB, b3.y, mB, b + 769); SEL(idxB, b3.z, mB, b + 770); SEL(idxB, b3.w, mB, b + 771);
#undef SEL

    // four interleaved butterfly chains
    #pragma unroll
    for (int off = 32; off >= 1; off >>= 1) {
        sA   += __shfl_xor(sA, off, 64);
        sB   += __shfl_xor(sB, off, 64);
        idxA  = min(idxA, __shfl_xor(idxA, off, 64));
        idxB  = min(idxB, __shfl_xor(idxB, off, 64));
    }

    // all lanes hold results; lanes 0/1 write rows A/B
    if (lane < 2) {
        const int row = rowA + lane;
        const int t = row >> 6;            // row / N_DIM (N=64)
        const int n = row & (N_DIM - 1);
        const float mlp = -__logf(lane == 0 ? sA : sB);
        const int   id  = (lane == 0) ? idxA : idxB;
        maxlpT[n * T_DIM + t]  = mlp;
        argmaxT[n * T_DIM + t] = id;
    }
}

// ---------------------------------------------------------------------------
// Kernel 2: one block (256 threads = 4 waves) per batch element n.
// keep mask -> wave shuffle scan (2 barriers total) -> LDS compaction -> out.
// Output layout (all float): [ score(N) | paths(T*N, (T,N) order) | out_lens(N) ]
// ---------------------------------------------------------------------------
__global__ __launch_bounds__(256) void ctc_scan(
    const float* __restrict__ maxlpT,
    const int*   __restrict__ argmaxT,
    const int*   __restrict__ in_lens,
    float*       __restrict__ out)
{
    constexpr int CHUNK = 8;               // 256*8 = 2048 >= T; 2000 % 8 == 0
    const int n    = blockIdx.x;
    const int tid  = threadIdx.x;
    const int lane = tid & 63;
    const int w    = tid >> 6;
    const int in_len = in_lens[n];
    const int*   am = argmaxT + n * T_DIM;
    const float* ml = maxlpT + n * T_DIM;

    __shared__ int   buf[T_DIM];           // compacted path values (8000 B)
    __shared__ int   wtot[4];
    __shared__ float wsum[4];

    const int t0 = tid * CHUNK;
    const bool live = (t0 < T_DIM);        // tid < 250

    int   my_am[CHUNK];
    bool  my_keep[CHUNK];
    int   cnt = 0;
    float sc  = 0.f;

    if (live) {
        const int4*   ap = reinterpret_cast<const int4*>(am + t0);     // 32B-aligned
        const float4* fp = reinterpret_cast<const float4*>(ml + t0);
        int4   a0 = ap[0], a1 = ap[1];
        float4 f0 = fp[0], f1 = fp[1];
        my_am[0] = a0.x; my_am[1] = a0.y; my_am[2] = a0.z; my_am[3] = a0.w;
        my_am[4] = a1.x; my_am[5] = a1.y; my_am[6] = a1.z; my_am[7] = a1.w;
        const float fv[CHUNK] = {f0.x, f0.y, f0.z, f0.w, f1.x, f1.y, f1.z, f1.w};

        int prev = (t0 > 0) ? am[t0 - 1] : -1;  // -1 never matches 0..V-1
        #pragma unroll
        for (int k = 0; k < CHUNK; ++k) {
            const int t = t0 + k;
            const int a = my_am[k];
            const bool kp = (a != BLANK) && (a != prev) && (t < in_len);
            my_keep[k] = kp;
            cnt += kp ? 1 : 0;
            if (t < in_len) sc += fv[k];
            prev = a;
        }
    } else {
        #pragma unroll
        for (int k = 0; k < CHUNK; ++k) { my_am[k] = 0; my_keep[k] = false; }
    }

    // wave-level inclusive scan of cnt (no barriers)
    int inc = cnt;
    #pragma unroll
    for (int off = 1; off < 64; off <<= 1) {
        int v = __shfl_up(inc, off, 64);
        if (lane >= off) inc += v;
    }

    // wave-level score sum
    float ss = sc;
    #pragma unroll
    for (int off = 32; off >= 1; off >>= 1)
        ss += __shfl_xor(ss, off, 64);

    if (lane == 63) wtot[w] = inc;
    if (lane == 0)  wsum[w] = ss;
    __syncthreads();                       // barrier 1

    int woff = 0;
    #pragma unroll
    for (int i = 0; i < 4; ++i) woff += (i < w) ? wtot[i] : 0;
    const int out_len = wtot[0] + wtot[1] + wtot[2] + wtot[3];

    // scatter kept values into LDS compaction buffer
    int pos = woff + inc - cnt;            // exclusive global prefix
    #pragma unroll
    for (int k = 0; k < CHUNK; ++k) {
        if (my_keep[k]) buf[pos++] = my_am[k];
    }
    __syncthreads();                       // barrier 2

    // paths: compacted inside out_len, raw argmax outside; (T,N) layout
    if (live) {
        #pragma unroll
        for (int k = 0; k < CHUNK; ++k) {
            const int t = t0 + k;
            const int v = (t < out_len) ? buf[t] : my_am[k];
            out[N_DIM + (size_t)t * N_DIM + n] = (float)v;
        }
    }

    if (tid == 0) {
        out[n] = (wsum[0] + wsum[1]) + (wsum[2] + wsum[3]);
        out[N_DIM + (size_t)T_DIM * N_DIM + n] = (float)out_len;
    }
}

extern "C" void kernel_launch(void* const* d_in, const int* in_sizes, int n_in,
                              void* d_out, int out_size, void* d_ws, size_t ws_size,
                              hipStream_t stream)
{
    const float* logits  = (const float*)d_in[0];
    const int*   in_lens = (const int*)d_in[1];
    float* out = (float*)d_out;

    float* maxlpT  = (float*)d_ws;
    int*   argmaxT = (int*)((char*)d_ws + (size_t)T_DIM * N_DIM * sizeof(float));

    // 32000 rows, 8 rows per block (2 per wave)
    ctc_rowreduce<<<(T_DIM * N_DIM) / 8, 256, 0, stream>>>(logits, maxlpT, argmaxT);
    ctc_scan<<<N_DIM, 256, 0, stream>>>(maxlpT, argmaxT, in_lens, out);
}